// Round 3
// baseline (366.774 us; speedup 1.0000x reference)
//
#include <hip/hip_runtime.h>

// HEALPix pad, p=1, n=128, C=128, B12=24 (B=2 x 12 faces), fp32.
// R3: latency-bound fix — 4 independent load/store pairs per thread
// (4 KB in flight per wave vs 1 KB), 4 interior blocks/plane + 1 border block.

#define NPLANE_OUT 16900   // 130*130

__device__ __forceinline__ float hp_face(const float* __restrict__ in, size_t baseoff,
                                         int q, int i, int j) {
  return in[baseoff + ((size_t)q << 21) + (i << 7) + j];
}

__device__ __forceinline__ float hp_val(const float* __restrict__ in, size_t baseoff,
                                        int type, int m, int face, int r, int col) {
  const int L = 127;
  if (r == 0) {
    if (col == 0) {  // TL corner
      if (type == 0) return hp_face(in, baseoff, (m + 2) & 3, 0, 0);
      if (type == 1) return 0.5f * (hp_face(in, baseoff, m, L, 0) +
                                    hp_face(in, baseoff, (m + 3) & 3, 0, L));
      return hp_face(in, baseoff, m, L, L);
    }
    if (col == 129) {  // TR corner
      if (type == 0) return hp_face(in, baseoff, (m + 1) & 3, L, 0);
      if (type == 1) return hp_face(in, baseoff, 4 + ((m + 1) & 3), L, 0);
      return hp_face(in, baseoff, 8 + ((m + 1) & 3), L, 0);
    }
    int j = col - 1;  // top row
    if (type == 0) return hp_face(in, baseoff, (m + 1) & 3, j, 0);
    if (type == 1) return hp_face(in, baseoff, m, L, j);
    return hp_face(in, baseoff, 4 + ((m + 1) & 3), L, j);
  }
  if (r == 129) {
    if (col == 0) {  // BL corner
      if (type == 0) return hp_face(in, baseoff, (m + 3) & 3, 0, L);
      if (type == 1) return hp_face(in, baseoff, 4 + ((m + 3) & 3), 0, L);
      return hp_face(in, baseoff, 8 + ((m + 3) & 3), 0, L);
    }
    if (col == 129) {  // BR corner
      if (type == 0) return hp_face(in, baseoff, 8 + m, 0, 0);
      if (type == 1) return 0.5f * (hp_face(in, baseoff, 8 + ((m + 3) & 3), 0, L) +
                                    hp_face(in, baseoff, 8 + m, L, 0));
      return hp_face(in, baseoff, 8 + ((m + 2) & 3), L, L);
    }
    int j = col - 1;  // bottom row
    if (type == 0) return hp_face(in, baseoff, 4 + m, 0, j);
    if (type == 1) return hp_face(in, baseoff, 8 + ((m + 3) & 3), 0, j);
    return hp_face(in, baseoff, 8 + ((m + 3) & 3), j, L);
  }
  int i = r - 1;
  if (col == 0) {  // left column
    if (type == 0) return hp_face(in, baseoff, (m + 3) & 3, 0, i);
    if (type == 1) return hp_face(in, baseoff, (m + 3) & 3, i, L);
    return hp_face(in, baseoff, 4 + m, i, L);
  }
  // col == 129, right column
  if (type == 0) return hp_face(in, baseoff, 4 + ((m + 1) & 3), i, 0);
  if (type == 1) return hp_face(in, baseoff, 8 + m, i, 0);
  return hp_face(in, baseoff, 8 + ((m + 1) & 3), L, i);
}

typedef float f4v __attribute__((ext_vector_type(4)));

__global__ __launch_bounds__(256) void CREDITHEALPix_90975997264316_kernel(
    const float* __restrict__ in, float* __restrict__ out) {
  int plane = blockIdx.y;      // 0..3071 : b12*128 + c
  int b12 = plane >> 7;
  int c = plane & 127;
  int batch = (b12 >= 12) ? 1 : 0;
  int face = b12 - batch * 12;
  int type = face >> 2;        // 0=north, 1=equatorial, 2=south
  int m = face & 3;
  size_t baseoff = (((size_t)batch * 1536) + (size_t)c) << 14;  // (batch*12*128+c)*16384
  float* __restrict__ oplane = out + (size_t)plane * NPLANE_OUT;

  if (blockIdx.x < 4) {
    // ---- interior: 1024 quads per block, 4 per thread, k-strided so every
    // instruction is lane-coalesced; loads batched ahead of stores for MLP ----
    const float* __restrict__ fsrc = in + baseoff + ((size_t)face << 21);
    int base = blockIdx.x * 1024 + threadIdx.x;
    f4v v[4];
#pragma unroll
    for (int k = 0; k < 4; ++k) {
      int iq = base + k * 256;
      v[k] = *(const f4v*)(fsrc + ((size_t)(iq >> 5) << 7) + ((iq & 31) << 2));
    }
#pragma unroll
    for (int k = 0; k < 4; ++k) {
      int iq = base + k * 256;
      int r = iq >> 5;
      int j4 = (iq & 31) << 2;
      __builtin_memcpy(oplane + (r + 1) * 130 + 1 + j4, &v[k], 16);
    }
  } else {
    // ---- border: 516 elements per plane ----
    for (int e = threadIdx.x; e < 516; e += 256) {
      int r, col;
      if (e < 130)      { r = 0;       col = e; }
      else if (e < 260) { r = 129;     col = e - 130; }
      else if (e < 388) { r = e - 259; col = 0; }        // rows 1..128, left
      else              { r = e - 387; col = 129; }      // rows 1..128, right
      oplane[r * 130 + col] = hp_val(in, baseoff, type, m, face, r, col);
    }
  }
}

extern "C" void kernel_launch(void* const* d_in, const int* in_sizes, int n_in,
                              void* d_out, int out_size, void* d_ws, size_t ws_size,
                              hipStream_t stream) {
  const float* in = (const float*)d_in[0];
  float* out = (float*)d_out;
  // grid.x: 4 interior blocks (4096 quads) + 1 border block, per plane
  dim3 grid(5, 3072, 1);
  dim3 block(256, 1, 1);
  CREDITHEALPix_90975997264316_kernel<<<grid, block, 0, stream>>>(in, out);
}